// Round 16
// baseline (135.450 us; speedup 1.0000x reference)
//
#include <hip/hip_runtime.h>
#include <math.h>

#define N_ROWS 131072   // 32*64*64
#define D 64
#define K 512
#define BLK 512                       // 8 waves (K1)
#define ROWS_PER_BLK 512
#define GRID (N_ROWS / ROWS_PER_BLK)  // 256 -> 1 block/CU for K1
#define MARGIN 4e-3f

// d_out layout (floats):
//   [0] loss ; [1..8388608] quantized NCHW ; [8388609] perplexity ;
//   [8388610..] encodings [131072,512]
// d_ws: [0,2048) counts u32[512]; [2048,2056) loss_acc u64 fixed-point

typedef __attribute__((ext_vector_type(8))) _Float16 f16x8;
typedef __attribute__((ext_vector_type(4))) float    f32x4;

#define MFMA(a, b, c) __builtin_amdgcn_mfma_f32_16x16x32_f16((a), (b), (c), 0, 0, 0)

// K1 LDS arena (137216 B): codebook region [0,131072) doubles as X staging.
#define OFF_EH   0        // [512 codes][128 B] fp16-hi, XOR-swizzled
#define OFF_EL   65536    // fp16-lo
#define OFF_XH   0        // phase A: [512 rows][128 B] fp16-hi (overwritten)
#define OFF_XL   65536    // phase A: fp16-lo
#define OFF_E2   131072   // f32[512]
#define OFF_IDX  133120   // i32[512]
#define OFF_REF  135168   // i32[512]
#define ARENA_SZ 137216

__device__ __forceinline__ unsigned pk2(_Float16 a, _Float16 b) {
    return (unsigned)__builtin_bit_cast(unsigned short, a) |
           ((unsigned)__builtin_bit_cast(unsigned short, b) << 16);
}

#define CT_ALL(M) M(0) M(1) M(2) M(3)
#define UPD(rt, s, ki) { \
    bool lt1 = (s) < s1_##rt; bool lt2 = (s) < s2_##rt; \
    s2_##rt = lt1 ? s1_##rt : (lt2 ? (s) : s2_##rt); \
    i2_##rt = lt1 ? i1_##rt : (lt2 ? (ki) : i2_##rt); \
    s1_##rt = lt1 ? (s) : s1_##rt; \
    i1_##rt = lt1 ? (ki) : i1_##rt; }

// One distance pass over the full codebook for 32 rows (2 row-tiles of 16).
// Dekker fp16 split, 3 product terms (lo*lo ~1.5e-5 << MARGIN dropped).
// C layout: col=lane&15 -> x-row; row=(lane>>4)*4+j -> code.
__device__ __forceinline__ void dist_pass(
    const char* ebase, const float* e2L, int fq, int fr,
    f16x8 xh0_0, f16x8 xh0_1, f16x8 xl0_0, f16x8 xl0_1,
    f16x8 xh1_0, f16x8 xh1_1, f16x8 xl1_0, f16x8 xl1_1,
    int* s_idxL, int* s_refL, int row0)
{
    float s1_0 = INFINITY, s2_0 = INFINITY, s1_1 = INFINITY, s2_1 = INFINITY;
    int   i1_0 = 0, i2_0 = 0, i1_1 = 0, i2_1 = 0;

    for (int cb = 0; cb < 8; ++cb) {
        const int cbBase = cb * 64 + fq * 4;

#define LDE2(ct) f32x4 e2q##ct = *(const f32x4*)(e2L + cb * 64 + ct * 16 + fq * 4);
        CT_ALL(LDE2)
#undef LDE2

#define LDE(ct) \
        const int c##ct = cb * 64 + ct * 16 + fr; \
        const char* rb##ct = ebase + c##ct * 128; \
        const unsigned xr##ct = (unsigned)((c##ct & 7) << 4); \
        f16x8 eh##ct##_0 = *(const f16x8*)(rb##ct + OFF_EH + (((unsigned)(fq*16 +  0)) ^ xr##ct)); \
        f16x8 eh##ct##_1 = *(const f16x8*)(rb##ct + OFF_EH + (((unsigned)(fq*16 + 64)) ^ xr##ct)); \
        f16x8 el##ct##_0 = *(const f16x8*)(rb##ct + OFF_EL + (((unsigned)(fq*16 +  0)) ^ xr##ct)); \
        f16x8 el##ct##_1 = *(const f16x8*)(rb##ct + OFF_EL + (((unsigned)(fq*16 + 64)) ^ xr##ct));
        CT_ALL(LDE)
#undef LDE

#define ACC1(rt, ct) \
        f32x4 a##rt##_##ct = {0.f, 0.f, 0.f, 0.f}; \
        a##rt##_##ct = MFMA(eh##ct##_0, xh##rt##_0, a##rt##_##ct); \
        a##rt##_##ct = MFMA(eh##ct##_1, xh##rt##_1, a##rt##_##ct); \
        a##rt##_##ct = MFMA(el##ct##_0, xh##rt##_0, a##rt##_##ct); \
        a##rt##_##ct = MFMA(el##ct##_1, xh##rt##_1, a##rt##_##ct); \
        a##rt##_##ct = MFMA(eh##ct##_0, xl##rt##_0, a##rt##_##ct); \
        a##rt##_##ct = MFMA(eh##ct##_1, xl##rt##_1, a##rt##_##ct);
#define ACC_CT(ct) ACC1(0, ct) ACC1(1, ct)
        CT_ALL(ACC_CT)
#undef ACC_CT
#undef ACC1

#define SCJ(rt, ct, j) { \
        float s = fmaf(-2.f, a##rt##_##ct[j], e2q##ct[j]); \
        int ki = cbBase + ct * 16 + j; \
        UPD(rt, s, ki) }
#define SC4(rt, ct) SCJ(rt, ct, 0) SCJ(rt, ct, 1) SCJ(rt, ct, 2) SCJ(rt, ct, 3)
#define SC_CT(ct) SC4(0, ct) SC4(1, ct)
        CT_ALL(SC_CT)
#undef SC_CT
#undef SC4
#undef SCJ
    }

    // cross-lane top-2 merge (fq groups 0..3 see disjoint codes)
#define MERGE(rt, off) { \
    float b1 = __shfl_xor(s1_##rt, off); int bi1 = __shfl_xor(i1_##rt, off); \
    float b2 = __shfl_xor(s2_##rt, off); int bi2 = __shfl_xor(i2_##rt, off); \
    bool bf = (b1 < s1_##rt) || (b1 == s1_##rt && bi1 < i1_##rt); \
    float c1 = bf ? b1 : s1_##rt; int ci1 = bf ? bi1 : i1_##rt; \
    float lw = bf ? s1_##rt : b1; int lwi = bf ? i1_##rt : bi1; \
    float d2 = bf ? b2 : s2_##rt; int di2 = bf ? bi2 : i2_##rt; \
    bool ds = (d2 < lw) || (d2 == lw && di2 < lwi); \
    s1_##rt = c1; i1_##rt = ci1; \
    s2_##rt = ds ? d2 : lw; i2_##rt = ds ? di2 : lwi; }
    MERGE(0, 16) MERGE(0, 32) MERGE(1, 16) MERGE(1, 32)
#undef MERGE

    if (fq == 0) {
        s_idxL[row0 + fr] = i1_0;
        s_refL[row0 + fr] = (s2_0 - s1_0 < MARGIN) ? i2_0 : -1;
        s_idxL[row0 + fr + 16] = i1_1;
        s_refL[row0 + fr + 16] = (s2_1 - s1_1 < MARGIN) ? i2_1 : -1;
    }
}

// K1: MFMA distance machine. Round-16: e2 computed in-kernel during P2
// (16-lane shfl_xor reduce over each code's float4s) -- removes the
// standalone e2 kernel + its launch. Writes packed (i1 | (ref+1)<<16)
// into the first 4 bytes of each row's enc slot.
__global__ __launch_bounds__(BLK, 2) void vq_dist_kernel(
    const float* __restrict__ in,     // [32,64,64,64] NCHW
    const float* __restrict__ emb,    // [512,64]
    float* __restrict__ enc_out)      // [N_ROWS, 512]
{
    __shared__ __align__(16) char s_arena[ARENA_SZ];
    float* e2L    = (float*)(s_arena + OFF_E2);
    int*   s_idxL = (int*)(s_arena + OFF_IDX);
    int*   s_refL = (int*)(s_arena + OFF_REF);

    const int tid  = threadIdx.x;
    const int lane = tid & 63;
    const int w    = tid >> 6;
    const int fr   = lane & 15;
    const int fq   = lane >> 4;

    // P0: stage x split into LDS [512 rows][128 B] fp16, XOR-swizzled
    {
        const int nn = blockIdx.x * ROWS_PER_BLK + tid;
        const int bb = nn >> 12, hww = nn & 4095;
        const float* xp = in + (size_t)bb * 262144 + hww;
        char* xhW = s_arena + OFF_XH;
        char* xlW = s_arena + OFF_XL;
        const unsigned rbase = (unsigned)tid * 128u;
        const unsigned rxor  = (unsigned)((tid & 7) << 4);
        #pragma unroll
        for (int i = 0; i < 64; i += 2) {
            float f0 = xp[i * 4096];
            float f1 = xp[(i + 1) * 4096];
            _Float16 h0 = (_Float16)f0; _Float16 l0 = (_Float16)(f0 - (float)h0);
            _Float16 h1 = (_Float16)f1; _Float16 l1 = (_Float16)(f1 - (float)h1);
            unsigned off = rbase + (((unsigned)(i * 2)) ^ rxor);
            *(unsigned*)(xhW + off) = pk2(h0, h1);
            *(unsigned*)(xlW + off) = pk2(l0, l1);
        }
    }
    __syncthreads();

    // P1: load ALL 4 row-tiles' X fragments (matching XOR on 16B offsets)
    const char* xb = s_arena;
    const int xr0 = w * 64 + fr;
#define LDX1(t, half) \
    *(const f16x8*)(xb + OFF_XH + (unsigned)(xr0 + t * 16) * 128u + \
        (((unsigned)(fq * 16 + half * 64)) ^ ((unsigned)(((xr0 + t * 16) & 7) << 4))))
#define LDX1L(t, half) \
    *(const f16x8*)(xb + OFF_XL + (unsigned)(xr0 + t * 16) * 128u + \
        (((unsigned)(fq * 16 + half * 64)) ^ ((unsigned)(((xr0 + t * 16) & 7) << 4))))
#define LDXF(t) \
    f16x8 xh##t##_0 = LDX1(t, 0); \
    f16x8 xh##t##_1 = LDX1(t, 1); \
    f16x8 xl##t##_0 = LDX1L(t, 0); \
    f16x8 xl##t##_1 = LDX1L(t, 1);
    LDXF(0) LDXF(1) LDXF(2) LDXF(3)
#undef LDXF
#undef LDX1
#undef LDX1L
    __syncthreads();

    // P2: overwrite LDS with split codebook (XOR-swizzled rows); compute e2
    // in the same sweep: the 16 lanes of each aligned 16-lane group handle
    // exactly one code's 16 float4s per iteration -> shfl_xor reduce.
    {
        char* eb = s_arena;
        #pragma unroll
        for (int it = 0; it < 16; ++it) {
            int j = tid + it * 512;            // float4 index, 0..8191
            int c = j >> 4, q = j & 15;        // code, quad-within-row
            float4 e = ((const float4*)emb)[j];
            _Float16 h0 = (_Float16)e.x; _Float16 l0 = (_Float16)(e.x - (float)h0);
            _Float16 h1 = (_Float16)e.y; _Float16 l1 = (_Float16)(e.y - (float)h1);
            _Float16 h2 = (_Float16)e.z; _Float16 l2 = (_Float16)(e.z - (float)h2);
            _Float16 h3 = (_Float16)e.w; _Float16 l3 = (_Float16)(e.w - (float)h3);
            unsigned xr = (unsigned)((c & 7) << 4);
            unsigned base = (unsigned)(c * 128) + (((unsigned)(q * 8)) ^ xr);
            *(uint2*)(eb + OFF_EH + base) = make_uint2(pk2(h0, h1), pk2(h2, h3));
            *(uint2*)(eb + OFF_EL + base) = make_uint2(pk2(l0, l1), pk2(l2, l3));

            float p = e.x * e.x;
            p = fmaf(e.y, e.y, p);
            p = fmaf(e.z, e.z, p);
            p = fmaf(e.w, e.w, p);
            p += __shfl_xor(p, 1);
            p += __shfl_xor(p, 2);
            p += __shfl_xor(p, 4);
            p += __shfl_xor(p, 8);
            if (q == 0) e2L[c] = p;
        }
    }
    __syncthreads();

    // P3: two distance passes for this wave's 64 rows
    dist_pass(s_arena, e2L, fq, fr,
              xh0_0, xh0_1, xl0_0, xl0_1, xh1_0, xh1_1, xl1_0, xl1_1,
              s_idxL, s_refL, w * 64);
    dist_pass(s_arena, e2L, fq, fr,
              xh2_0, xh2_1, xl2_0, xl2_1, xh3_0, xh3_1, xl3_0, xl3_1,
              s_idxL, s_refL, w * 64 + 32);

    // pack (i1, ref) into the row's enc slot (same wave produced both)
    {
        const int n = blockIdx.x * ROWS_PER_BLK + tid;
        int i1 = s_idxL[tid];
        int ir = s_refL[tid];
        *(int*)(enc_out + (size_t)n * K) = i1 | ((ir + 1) << 16);
    }
}

// K23 (fused R16): refine + hist + quant(NT) + loss, one barrier, then
// 4-wave one-hot expansion straight from LDS s_idx (final idx never
// round-trips HBM). 512 blocks x 256 threads, 256 rows/block.
__global__ __launch_bounds__(256) void vq_out_kernel(
    const float* __restrict__ in,
    const float* __restrict__ emb,
    unsigned int* __restrict__ counts,
    unsigned long long* __restrict__ loss_acc,
    float* __restrict__ quant_out,
    float* __restrict__ enc)
{
    __shared__ unsigned int s_hist[K];
    __shared__ int s_idx[256];
    __shared__ double s_red[256];
    const int tid = threadIdx.x;
    const int n = blockIdx.x * 256 + tid;
    s_hist[tid] = 0u; s_hist[tid + 256] = 0u;
    __syncthreads();

    // phase A: refine + final idx + hist + quant(NT) + loss (thread = row)
    const int b = n >> 12, hw = n & 4095;
    const float* xin = in + (size_t)b * 262144 + hw;
    const int packed = *(const int*)(enc + (size_t)n * K);
    int i1 = packed & 0xFFFF;
    const int ir = (packed >> 16) - 1;
    if (ir >= 0) {   // fp64 refinement on near-ties (argmin fp64-exact)
        double dA = 0.0, dB = 0.0;
        const float* eA = emb + i1 * D;
        const float* eB = emb + ir * D;
        for (int d = 0; d < D; ++d) {
            double xv = (double)xin[d * 4096];
            double tA = xv - (double)eA[d]; dA = fma(tA, tA, dA);
            double tB = xv - (double)eB[d]; dB = fma(tB, tB, dB);
        }
        if (dB < dA || (dB == dA && ir < i1)) i1 = ir;
    }
    s_idx[tid] = i1;
    atomicAdd(&s_hist[i1], 1u);

    const float4* eq = (const float4*)(emb + (size_t)i1 * D);
    float* qout = quant_out + (size_t)b * 262144 + hw;
    float lsum = 0.f;
    #pragma unroll
    for (int i = 0; i < 16; ++i) {
        float4 q = eq[i];
        float x0 = xin[(4 * i + 0) * 4096], x1 = xin[(4 * i + 1) * 4096];
        float x2 = xin[(4 * i + 2) * 4096], x3 = xin[(4 * i + 3) * 4096];
        float d0 = q.x - x0; lsum = fmaf(d0, d0, lsum);
        float d1 = q.y - x1; lsum = fmaf(d1, d1, lsum);
        float d2 = q.z - x2; lsum = fmaf(d2, d2, lsum);
        float d3 = q.w - x3; lsum = fmaf(d3, d3, lsum);
        __builtin_nontemporal_store(q.x, &qout[(4 * i + 0) * 4096]);
        __builtin_nontemporal_store(q.y, &qout[(4 * i + 1) * 4096]);
        __builtin_nontemporal_store(q.z, &qout[(4 * i + 2) * 4096]);
        __builtin_nontemporal_store(q.w, &qout[(4 * i + 3) * 4096]);
    }
    s_red[tid] = (double)lsum;
    __syncthreads();

    // phase B: one-hot expansion, 4 waves x 64 rows, dense NT 16B stores
    {
        const int wv   = tid >> 6;
        const int lane = tid & 63;
        const int r0   = wv * 64;
        float* brow = enc + ((size_t)blockIdx.x * 256 + r0) * K;
        const int c0 = lane * 4;
        #pragma unroll 8
        for (int i = 0; i < 64; ++i) {
            const int idx = s_idx[r0 + i];
            float* rp = brow + (size_t)i * K;
            f32x4 v0, v1;
            v0.x = (c0 + 0 == idx) ? 1.f : 0.f;
            v0.y = (c0 + 1 == idx) ? 1.f : 0.f;
            v0.z = (c0 + 2 == idx) ? 1.f : 0.f;
            v0.w = (c0 + 3 == idx) ? 1.f : 0.f;
            v1.x = (256 + c0 + 0 == idx) ? 1.f : 0.f;
            v1.y = (256 + c0 + 1 == idx) ? 1.f : 0.f;
            v1.z = (256 + c0 + 2 == idx) ? 1.f : 0.f;
            v1.w = (256 + c0 + 3 == idx) ? 1.f : 0.f;
            __builtin_nontemporal_store(v0, (f32x4*)(rp + c0));
            __builtin_nontemporal_store(v1, (f32x4*)(rp + 256 + c0));
        }
    }

    // epilogue: loss tree-reduce + hist flush
    __syncthreads();
    for (int s = 128; s > 0; s >>= 1) {
        if (tid < s) s_red[tid] += s_red[tid + s];
        __syncthreads();
    }
    if (tid == 0) {
        unsigned long long q =
            (unsigned long long)(long long)llrint(s_red[0] * 1073741824.0);
        atomicAdd(loss_acc, q);
    }
    {
        unsigned int c0h = s_hist[tid];
        if (c0h) atomicAdd(&counts[tid], c0h);
        unsigned int c1h = s_hist[tid + 256];
        if (c1h) atomicAdd(&counts[tid + 256], c1h);
    }
}

__global__ __launch_bounds__(512) void vq_final_kernel(
    const unsigned int* __restrict__ counts,
    const unsigned long long* __restrict__ loss_acc,
    float* __restrict__ out_loss,
    float* __restrict__ out_perp)
{
    __shared__ double sp[512];
    int t = threadIdx.x;
    double p = (double)counts[t] / (double)N_ROWS;
    sp[t] = p * log(p + 1e-10);
    __syncthreads();
    for (int s = 256; s > 0; s >>= 1) {
        if (t < s) sp[t] += sp[t + s];
        __syncthreads();
    }
    if (t == 0) {
        double ls = (double)(long long)(*loss_acc) * (1.0 / 1073741824.0);
        *out_loss = (float)(0.25 * ls / 8388608.0);
        *out_perp = (float)exp(-sp[0]);
    }
}

extern "C" void kernel_launch(void* const* d_in, const int* in_sizes, int n_in,
                              void* d_out, int out_size, void* d_ws, size_t ws_size,
                              hipStream_t stream) {
    const float* in  = (const float*)d_in[0];
    const float* emb = (const float*)d_in[1];
    float* out = (float*)d_out;

    unsigned int* counts = (unsigned int*)d_ws;
    unsigned long long* loss_acc = (unsigned long long*)((char*)d_ws + 2048);

    hipMemsetAsync(d_ws, 0, 2056, stream);
    vq_dist_kernel<<<GRID, BLK, 0, stream>>>(in, emb, out + 8388610);
    vq_out_kernel<<<N_ROWS / 256, 256, 0, stream>>>(in, emb, counts, loss_acc,
                                                    out + 1, out + 8388610);
    vq_final_kernel<<<1, 512, 0, stream>>>(counts, loss_acc, out, out + 8388609);
}

// Round 17
// 125.304 us; speedup vs baseline: 1.0810x; 1.0810x over previous
//
#include <hip/hip_runtime.h>
#include <math.h>

#define N_ROWS 131072   // 32*64*64
#define D 64
#define K 512
#define BLK 512                       // 8 waves (K1)
#define ROWS_PER_BLK 512
#define GRID (N_ROWS / ROWS_PER_BLK)  // 256 -> 1 block/CU for K1
#define MARGIN 4e-3f

// d_out layout (floats):
//   [0] loss ; [1..8388608] quantized NCHW ; [8388609] perplexity ;
//   [8388610..] encodings [131072,512]
// d_ws: [0,2048) counts u32[512]; [2048,2056) loss_acc u64 fixed-point

typedef __attribute__((ext_vector_type(8))) _Float16 f16x8;
typedef __attribute__((ext_vector_type(4))) float    f32x4;

#define MFMA(a, b, c) __builtin_amdgcn_mfma_f32_16x16x32_f16((a), (b), (c), 0, 0, 0)

// K1 LDS arena (137216 B): codebook region [0,131072) doubles as X staging.
#define OFF_EH   0        // [512 codes][128 B] fp16-hi, XOR-swizzled
#define OFF_EL   65536    // fp16-lo
#define OFF_XH   0        // phase A: [512 rows][128 B] fp16-hi (overwritten)
#define OFF_XL   65536    // phase A: fp16-lo
#define OFF_E2   131072   // f32[512]
#define OFF_IDX  133120   // i32[512]
#define OFF_REF  135168   // i32[512]
#define ARENA_SZ 137216

__device__ __forceinline__ unsigned pk2(_Float16 a, _Float16 b) {
    return (unsigned)__builtin_bit_cast(unsigned short, a) |
           ((unsigned)__builtin_bit_cast(unsigned short, b) << 16);
}

#define CT_ALL(M) M(0) M(1) M(2) M(3)
#define UPD(rt, s, ki) { \
    bool lt1 = (s) < s1_##rt; bool lt2 = (s) < s2_##rt; \
    s2_##rt = lt1 ? s1_##rt : (lt2 ? (s) : s2_##rt); \
    i2_##rt = lt1 ? i1_##rt : (lt2 ? (ki) : i2_##rt); \
    s1_##rt = lt1 ? (s) : s1_##rt; \
    i1_##rt = lt1 ? (ki) : i1_##rt; }

// One distance pass over the full codebook for 32 rows (2 row-tiles of 16).
// Dekker fp16 split, 3 product terms (lo*lo ~1.5e-5 << MARGIN dropped).
// C layout: col=lane&15 -> x-row; row=(lane>>4)*4+j -> code.
__device__ __forceinline__ void dist_pass(
    const char* ebase, const float* e2L, int fq, int fr,
    f16x8 xh0_0, f16x8 xh0_1, f16x8 xl0_0, f16x8 xl0_1,
    f16x8 xh1_0, f16x8 xh1_1, f16x8 xl1_0, f16x8 xl1_1,
    int* s_idxL, int* s_refL, int row0)
{
    float s1_0 = INFINITY, s2_0 = INFINITY, s1_1 = INFINITY, s2_1 = INFINITY;
    int   i1_0 = 0, i2_0 = 0, i1_1 = 0, i2_1 = 0;

    for (int cb = 0; cb < 8; ++cb) {
        const int cbBase = cb * 64 + fq * 4;

#define LDE2(ct) f32x4 e2q##ct = *(const f32x4*)(e2L + cb * 64 + ct * 16 + fq * 4);
        CT_ALL(LDE2)
#undef LDE2

#define LDE(ct) \
        const int c##ct = cb * 64 + ct * 16 + fr; \
        const char* rb##ct = ebase + c##ct * 128; \
        const unsigned xr##ct = (unsigned)((c##ct & 7) << 4); \
        f16x8 eh##ct##_0 = *(const f16x8*)(rb##ct + OFF_EH + (((unsigned)(fq*16 +  0)) ^ xr##ct)); \
        f16x8 eh##ct##_1 = *(const f16x8*)(rb##ct + OFF_EH + (((unsigned)(fq*16 + 64)) ^ xr##ct)); \
        f16x8 el##ct##_0 = *(const f16x8*)(rb##ct + OFF_EL + (((unsigned)(fq*16 +  0)) ^ xr##ct)); \
        f16x8 el##ct##_1 = *(const f16x8*)(rb##ct + OFF_EL + (((unsigned)(fq*16 + 64)) ^ xr##ct));
        CT_ALL(LDE)
#undef LDE

#define ACC1(rt, ct) \
        f32x4 a##rt##_##ct = {0.f, 0.f, 0.f, 0.f}; \
        a##rt##_##ct = MFMA(eh##ct##_0, xh##rt##_0, a##rt##_##ct); \
        a##rt##_##ct = MFMA(eh##ct##_1, xh##rt##_1, a##rt##_##ct); \
        a##rt##_##ct = MFMA(el##ct##_0, xh##rt##_0, a##rt##_##ct); \
        a##rt##_##ct = MFMA(el##ct##_1, xh##rt##_1, a##rt##_##ct); \
        a##rt##_##ct = MFMA(eh##ct##_0, xl##rt##_0, a##rt##_##ct); \
        a##rt##_##ct = MFMA(eh##ct##_1, xl##rt##_1, a##rt##_##ct);
#define ACC_CT(ct) ACC1(0, ct) ACC1(1, ct)
        CT_ALL(ACC_CT)
#undef ACC_CT
#undef ACC1

#define SCJ(rt, ct, j) { \
        float s = fmaf(-2.f, a##rt##_##ct[j], e2q##ct[j]); \
        int ki = cbBase + ct * 16 + j; \
        UPD(rt, s, ki) }
#define SC4(rt, ct) SCJ(rt, ct, 0) SCJ(rt, ct, 1) SCJ(rt, ct, 2) SCJ(rt, ct, 3)
#define SC_CT(ct) SC4(0, ct) SC4(1, ct)
        CT_ALL(SC_CT)
#undef SC_CT
#undef SC4
#undef SCJ
    }

    // cross-lane top-2 merge (fq groups 0..3 see disjoint codes)
#define MERGE(rt, off) { \
    float b1 = __shfl_xor(s1_##rt, off); int bi1 = __shfl_xor(i1_##rt, off); \
    float b2 = __shfl_xor(s2_##rt, off); int bi2 = __shfl_xor(i2_##rt, off); \
    bool bf = (b1 < s1_##rt) || (b1 == s1_##rt && bi1 < i1_##rt); \
    float c1 = bf ? b1 : s1_##rt; int ci1 = bf ? bi1 : i1_##rt; \
    float lw = bf ? s1_##rt : b1; int lwi = bf ? i1_##rt : bi1; \
    float d2 = bf ? b2 : s2_##rt; int di2 = bf ? bi2 : i2_##rt; \
    bool ds = (d2 < lw) || (d2 == lw && di2 < lwi); \
    s1_##rt = c1; i1_##rt = ci1; \
    s2_##rt = ds ? d2 : lw; i2_##rt = ds ? di2 : lwi; }
    MERGE(0, 16) MERGE(0, 32) MERGE(1, 16) MERGE(1, 32)
#undef MERGE

    if (fq == 0) {
        s_idxL[row0 + fr] = i1_0;
        s_refL[row0 + fr] = (s2_0 - s1_0 < MARGIN) ? i2_0 : -1;
        s_idxL[row0 + fr + 16] = i1_1;
        s_refL[row0 + fr + 16] = (s2_1 - s1_1 < MARGIN) ? i2_1 : -1;
    }
}

// K1: MFMA distance machine + e2 in-kernel + (R17) fp64 tie-refine moved
// here so it emits FINAL indices. Writes idx (as float bit pattern, TBAA-
// safe) into BOTH the enc row head (for enc-blocks) and the row's quant-d0
// slot (for quant-blocks) -- each consumer reads a cell only it overwrites.
__global__ __launch_bounds__(BLK, 2) void vq_dist_kernel(
    const float* __restrict__ in,     // [32,64,64,64] NCHW
    const float* __restrict__ emb,    // [512,64]
    float* __restrict__ quant_out,    // NCHW
    float* __restrict__ enc_out)      // [N_ROWS, 512]
{
    __shared__ __align__(16) char s_arena[ARENA_SZ];
    float* e2L    = (float*)(s_arena + OFF_E2);
    int*   s_idxL = (int*)(s_arena + OFF_IDX);
    int*   s_refL = (int*)(s_arena + OFF_REF);

    const int tid  = threadIdx.x;
    const int lane = tid & 63;
    const int w    = tid >> 6;
    const int fr   = lane & 15;
    const int fq   = lane >> 4;

    // P0: stage x split into LDS [512 rows][128 B] fp16, XOR-swizzled
    {
        const int nn = blockIdx.x * ROWS_PER_BLK + tid;
        const int bb = nn >> 12, hww = nn & 4095;
        const float* xp = in + (size_t)bb * 262144 + hww;
        char* xhW = s_arena + OFF_XH;
        char* xlW = s_arena + OFF_XL;
        const unsigned rbase = (unsigned)tid * 128u;
        const unsigned rxor  = (unsigned)((tid & 7) << 4);
        #pragma unroll
        for (int i = 0; i < 64; i += 2) {
            float f0 = xp[i * 4096];
            float f1 = xp[(i + 1) * 4096];
            _Float16 h0 = (_Float16)f0; _Float16 l0 = (_Float16)(f0 - (float)h0);
            _Float16 h1 = (_Float16)f1; _Float16 l1 = (_Float16)(f1 - (float)h1);
            unsigned off = rbase + (((unsigned)(i * 2)) ^ rxor);
            *(unsigned*)(xhW + off) = pk2(h0, h1);
            *(unsigned*)(xlW + off) = pk2(l0, l1);
        }
    }
    __syncthreads();

    // P1: load ALL 4 row-tiles' X fragments (matching XOR on 16B offsets)
    const char* xb = s_arena;
    const int xr0 = w * 64 + fr;
#define LDX1(t, half) \
    *(const f16x8*)(xb + OFF_XH + (unsigned)(xr0 + t * 16) * 128u + \
        (((unsigned)(fq * 16 + half * 64)) ^ ((unsigned)(((xr0 + t * 16) & 7) << 4))))
#define LDX1L(t, half) \
    *(const f16x8*)(xb + OFF_XL + (unsigned)(xr0 + t * 16) * 128u + \
        (((unsigned)(fq * 16 + half * 64)) ^ ((unsigned)(((xr0 + t * 16) & 7) << 4))))
#define LDXF(t) \
    f16x8 xh##t##_0 = LDX1(t, 0); \
    f16x8 xh##t##_1 = LDX1(t, 1); \
    f16x8 xl##t##_0 = LDX1L(t, 0); \
    f16x8 xl##t##_1 = LDX1L(t, 1);
    LDXF(0) LDXF(1) LDXF(2) LDXF(3)
#undef LDXF
#undef LDX1
#undef LDX1L
    __syncthreads();

    // P2: overwrite LDS with split codebook (XOR-swizzled rows); e2 in the
    // same sweep via 16-lane shfl_xor reduce.
    {
        char* eb = s_arena;
        #pragma unroll
        for (int it = 0; it < 16; ++it) {
            int j = tid + it * 512;            // float4 index, 0..8191
            int c = j >> 4, q = j & 15;        // code, quad-within-row
            float4 e = ((const float4*)emb)[j];
            _Float16 h0 = (_Float16)e.x; _Float16 l0 = (_Float16)(e.x - (float)h0);
            _Float16 h1 = (_Float16)e.y; _Float16 l1 = (_Float16)(e.y - (float)h1);
            _Float16 h2 = (_Float16)e.z; _Float16 l2 = (_Float16)(e.z - (float)h2);
            _Float16 h3 = (_Float16)e.w; _Float16 l3 = (_Float16)(e.w - (float)h3);
            unsigned xr = (unsigned)((c & 7) << 4);
            unsigned base = (unsigned)(c * 128) + (((unsigned)(q * 8)) ^ xr);
            *(uint2*)(eb + OFF_EH + base) = make_uint2(pk2(h0, h1), pk2(h2, h3));
            *(uint2*)(eb + OFF_EL + base) = make_uint2(pk2(l0, l1), pk2(l2, l3));

            float p = e.x * e.x;
            p = fmaf(e.y, e.y, p);
            p = fmaf(e.z, e.z, p);
            p = fmaf(e.w, e.w, p);
            p += __shfl_xor(p, 1);
            p += __shfl_xor(p, 2);
            p += __shfl_xor(p, 4);
            p += __shfl_xor(p, 8);
            if (q == 0) e2L[c] = p;
        }
    }
    __syncthreads();

    // P3: two distance passes for this wave's 64 rows
    dist_pass(s_arena, e2L, fq, fr,
              xh0_0, xh0_1, xl0_0, xl0_1, xh1_0, xh1_1, xl1_0, xl1_1,
              s_idxL, s_refL, w * 64);
    dist_pass(s_arena, e2L, fq, fr,
              xh2_0, xh2_1, xl2_0, xl2_1, xh3_0, xh3_1, xl3_0, xl3_1,
              s_idxL, s_refL, w * 64 + 32);

    // P4: fp64 tie-refine (rare) + dual final-idx write
    {
        const int n = blockIdx.x * ROWS_PER_BLK + tid;
        const int b = n >> 12, hw = n & 4095;
        int i1 = s_idxL[tid];
        const int ir = s_refL[tid];
        if (ir >= 0) {   // near-tie: exact fp64 distance from global x
            const float* xin = in + (size_t)b * 262144 + hw;
            double dA = 0.0, dB = 0.0;
            const float* eA = emb + i1 * D;
            const float* eB = emb + ir * D;
            for (int d = 0; d < D; ++d) {
                double xv = (double)xin[d * 4096];
                double tA = xv - (double)eA[d]; dA = fma(tA, tA, dA);
                double tB = xv - (double)eB[d]; dB = fma(tB, tB, dB);
            }
            if (dB < dA || (dB == dA && ir < i1)) i1 = ir;
        }
        const float fbits = __int_as_float(i1);
        enc_out[(size_t)n * K] = fbits;                 // for enc-blocks
        quant_out[(size_t)b * 262144 + hw] = fbits;     // for quant-blocks
    }
}

// K23 (R17): ONE grid, two block types, interleaved 4 enc : 1 quant so the
// 268 MB one-hot stream and the 67 MB quant stream share the write pipe
// instead of serializing as two dispatches.
__global__ __launch_bounds__(256) void vq_out_kernel(
    const float* __restrict__ in,
    const float* __restrict__ emb,
    unsigned int* __restrict__ counts,
    unsigned long long* __restrict__ loss_acc,
    float* __restrict__ quant_out,
    float* __restrict__ enc)
{
    __shared__ unsigned int s_hist[K];
    __shared__ double s_red[256];
    const int tid = threadIdx.x;
    const int grp = blockIdx.x / 5;
    const int sub = blockIdx.x % 5;

    if (sub < 4) {
        // ---- enc block: 64 rows, one-hot NT expansion ----
        const int eb   = grp * 4 + sub;        // 0..2047
        const int wv   = tid >> 6;
        const int lane = tid & 63;
        const size_t row0 = (size_t)eb * 64 + (size_t)wv * 16;

        int idxs[16];
        #pragma unroll
        for (int i = 0; i < 16; ++i)
            idxs[i] = __float_as_int(enc[(row0 + i) * K]);

        const int c0 = lane * 4;
        #pragma unroll
        for (int i = 0; i < 16; ++i) {
            const int idx = idxs[i];
            float* rp = enc + (row0 + i) * K;
            f32x4 v0, v1;
            v0.x = (c0 + 0 == idx) ? 1.f : 0.f;
            v0.y = (c0 + 1 == idx) ? 1.f : 0.f;
            v0.z = (c0 + 2 == idx) ? 1.f : 0.f;
            v0.w = (c0 + 3 == idx) ? 1.f : 0.f;
            v1.x = (256 + c0 + 0 == idx) ? 1.f : 0.f;
            v1.y = (256 + c0 + 1 == idx) ? 1.f : 0.f;
            v1.z = (256 + c0 + 2 == idx) ? 1.f : 0.f;
            v1.w = (256 + c0 + 3 == idx) ? 1.f : 0.f;
            __builtin_nontemporal_store(v0, (f32x4*)(rp + c0));
            __builtin_nontemporal_store(v1, (f32x4*)(rp + 256 + c0));
        }
        return;
    }

    // ---- quant block: 256 rows -> hist + quant(NT) + loss ----
    const int n = grp * 256 + tid;             // grp = 0..511
    s_hist[tid] = 0u; s_hist[tid + 256] = 0u;
    __syncthreads();

    const int b = n >> 12, hw = n & 4095;
    const float* xin = in + (size_t)b * 262144 + hw;
    const int i1 = __float_as_int(quant_out[(size_t)b * 262144 + hw]);
    atomicAdd(&s_hist[i1], 1u);

    const float4* eq = (const float4*)(emb + (size_t)i1 * D);
    float* qout = quant_out + (size_t)b * 262144 + hw;
    float lsum = 0.f;
    #pragma unroll
    for (int i = 0; i < 16; ++i) {
        float4 q = eq[i];
        float x0 = xin[(4 * i + 0) * 4096], x1 = xin[(4 * i + 1) * 4096];
        float x2 = xin[(4 * i + 2) * 4096], x3 = xin[(4 * i + 3) * 4096];
        float d0 = q.x - x0; lsum = fmaf(d0, d0, lsum);
        float d1 = q.y - x1; lsum = fmaf(d1, d1, lsum);
        float d2 = q.z - x2; lsum = fmaf(d2, d2, lsum);
        float d3 = q.w - x3; lsum = fmaf(d3, d3, lsum);
        __builtin_nontemporal_store(q.x, &qout[(4 * i + 0) * 4096]);
        __builtin_nontemporal_store(q.y, &qout[(4 * i + 1) * 4096]);
        __builtin_nontemporal_store(q.z, &qout[(4 * i + 2) * 4096]);
        __builtin_nontemporal_store(q.w, &qout[(4 * i + 3) * 4096]);
    }

    s_red[tid] = (double)lsum;
    __syncthreads();
    for (int s = 128; s > 0; s >>= 1) {
        if (tid < s) s_red[tid] += s_red[tid + s];
        __syncthreads();
    }
    if (tid == 0) {
        unsigned long long q =
            (unsigned long long)(long long)llrint(s_red[0] * 1073741824.0);
        atomicAdd(loss_acc, q);
    }
    {
        unsigned int c0h = s_hist[tid];
        if (c0h) atomicAdd(&counts[tid], c0h);
        unsigned int c1h = s_hist[tid + 256];
        if (c1h) atomicAdd(&counts[tid + 256], c1h);
    }
}

__global__ __launch_bounds__(512) void vq_final_kernel(
    const unsigned int* __restrict__ counts,
    const unsigned long long* __restrict__ loss_acc,
    float* __restrict__ out_loss,
    float* __restrict__ out_perp)
{
    __shared__ double sp[512];
    int t = threadIdx.x;
    double p = (double)counts[t] / (double)N_ROWS;
    sp[t] = p * log(p + 1e-10);
    __syncthreads();
    for (int s = 256; s > 0; s >>= 1) {
        if (t < s) sp[t] += sp[t + s];
        __syncthreads();
    }
    if (t == 0) {
        double ls = (double)(long long)(*loss_acc) * (1.0 / 1073741824.0);
        *out_loss = (float)(0.25 * ls / 8388608.0);
        *out_perp = (float)exp(-sp[0]);
    }
}

extern "C" void kernel_launch(void* const* d_in, const int* in_sizes, int n_in,
                              void* d_out, int out_size, void* d_ws, size_t ws_size,
                              hipStream_t stream) {
    const float* in  = (const float*)d_in[0];
    const float* emb = (const float*)d_in[1];
    float* out = (float*)d_out;

    unsigned int* counts = (unsigned int*)d_ws;
    unsigned long long* loss_acc = (unsigned long long*)((char*)d_ws + 2048);

    hipMemsetAsync(d_ws, 0, 2056, stream);
    vq_dist_kernel<<<GRID, BLK, 0, stream>>>(in, emb, out + 1, out + 8388610);
    vq_out_kernel<<<2560, 256, 0, stream>>>(in, emb, counts, loss_acc,
                                            out + 1, out + 8388610);
    vq_final_kernel<<<1, 512, 0, stream>>>(counts, loss_acc, out, out + 8388609);
}

// Round 18
// 123.352 us; speedup vs baseline: 1.0981x; 1.0158x over previous
//
#include <hip/hip_runtime.h>
#include <math.h>

#define N_ROWS 131072   // 32*64*64
#define D 64
#define K 512
#define BLK 512                       // 8 waves (K1)
#define ROWS_PER_BLK 512
#define GRID (N_ROWS / ROWS_PER_BLK)  // 256 -> 1 block/CU for K1
#define MARGIN 4e-3f

// d_out layout (floats):
//   [0] loss ; [1..8388608] quantized NCHW ; [8388609] perplexity ;
//   [8388610..] encodings [131072,512]
// d_ws: [0,2048) counts u32[512]; [2048,2056) loss_acc u64 fixed-point

typedef __attribute__((ext_vector_type(8))) _Float16 f16x8;
typedef __attribute__((ext_vector_type(4))) float    f32x4;

#define MFMA(a, b, c) __builtin_amdgcn_mfma_f32_16x16x32_f16((a), (b), (c), 0, 0, 0)

// K1 LDS arena (137216 B): codebook region [0,131072) doubles as X staging.
#define OFF_EH   0        // [512 codes][128 B] fp16-hi, XOR-swizzled
#define OFF_EL   65536    // fp16-lo
#define OFF_XH   0        // phase A: [512 rows][128 B] fp16-hi (overwritten)
#define OFF_XL   65536    // phase A: fp16-lo
#define OFF_E2   131072   // f32[512]
#define OFF_IDX  133120   // i32[512]
#define OFF_REF  135168   // i32[512]
#define ARENA_SZ 137216

__device__ __forceinline__ unsigned pk2(_Float16 a, _Float16 b) {
    return (unsigned)__builtin_bit_cast(unsigned short, a) |
           ((unsigned)__builtin_bit_cast(unsigned short, b) << 16);
}

#define CT_ALL(M) M(0) M(1) M(2) M(3)
#define RT_ALL(M) M(0) M(1) M(2) M(3)

// K1: MFMA distance machine. R18: SINGLE cb pass covering all 4 row-tiles
// (e-fragment LDS reads halved: each 16-frag load now feeds 4 tiles' MFMAs
// instead of 2; removes the second pass's loop+merge overhead).
// Emits FINAL indices (fp64 tie-refine in tail) as float bit patterns into
// both the enc row head and the row's quant-d0 slot.
__global__ __launch_bounds__(BLK, 2) void vq_dist_kernel(
    const float* __restrict__ in,     // [32,64,64,64] NCHW
    const float* __restrict__ emb,    // [512,64]
    float* __restrict__ quant_out,    // NCHW
    float* __restrict__ enc_out)      // [N_ROWS, 512]
{
    __shared__ __align__(16) char s_arena[ARENA_SZ];
    float* e2L    = (float*)(s_arena + OFF_E2);
    int*   s_idxL = (int*)(s_arena + OFF_IDX);
    int*   s_refL = (int*)(s_arena + OFF_REF);

    const int tid  = threadIdx.x;
    const int lane = tid & 63;
    const int w    = tid >> 6;
    const int fr   = lane & 15;
    const int fq   = lane >> 4;

    // P0: stage x split into LDS [512 rows][128 B] fp16, XOR-swizzled
    {
        const int nn = blockIdx.x * ROWS_PER_BLK + tid;
        const int bb = nn >> 12, hww = nn & 4095;
        const float* xp = in + (size_t)bb * 262144 + hww;
        char* xhW = s_arena + OFF_XH;
        char* xlW = s_arena + OFF_XL;
        const unsigned rbase = (unsigned)tid * 128u;
        const unsigned rxor  = (unsigned)((tid & 7) << 4);
        #pragma unroll
        for (int i = 0; i < 64; i += 2) {
            float f0 = xp[i * 4096];
            float f1 = xp[(i + 1) * 4096];
            _Float16 h0 = (_Float16)f0; _Float16 l0 = (_Float16)(f0 - (float)h0);
            _Float16 h1 = (_Float16)f1; _Float16 l1 = (_Float16)(f1 - (float)h1);
            unsigned off = rbase + (((unsigned)(i * 2)) ^ rxor);
            *(unsigned*)(xhW + off) = pk2(h0, h1);
            *(unsigned*)(xlW + off) = pk2(l0, l1);
        }
    }
    __syncthreads();

    // P1: load ALL 4 row-tiles' X fragments (matching XOR on 16B offsets)
    const char* xb = s_arena;
    const int xr0 = w * 64 + fr;
#define LDX1(t, half) \
    *(const f16x8*)(xb + OFF_XH + (unsigned)(xr0 + t * 16) * 128u + \
        (((unsigned)(fq * 16 + half * 64)) ^ ((unsigned)(((xr0 + t * 16) & 7) << 4))))
#define LDX1L(t, half) \
    *(const f16x8*)(xb + OFF_XL + (unsigned)(xr0 + t * 16) * 128u + \
        (((unsigned)(fq * 16 + half * 64)) ^ ((unsigned)(((xr0 + t * 16) & 7) << 4))))
#define LDXF(t) \
    f16x8 xh##t##_0 = LDX1(t, 0); \
    f16x8 xh##t##_1 = LDX1(t, 1); \
    f16x8 xl##t##_0 = LDX1L(t, 0); \
    f16x8 xl##t##_1 = LDX1L(t, 1);
    RT_ALL(LDXF)
#undef LDXF
#undef LDX1
#undef LDX1L
    __syncthreads();

    // P2: overwrite LDS with split codebook (XOR-swizzled rows); e2 in the
    // same sweep via 16-lane shfl_xor reduce.
    {
        char* eb = s_arena;
        #pragma unroll
        for (int it = 0; it < 16; ++it) {
            int j = tid + it * 512;            // float4 index, 0..8191
            int c = j >> 4, q = j & 15;        // code, quad-within-row
            float4 e = ((const float4*)emb)[j];
            _Float16 h0 = (_Float16)e.x; _Float16 l0 = (_Float16)(e.x - (float)h0);
            _Float16 h1 = (_Float16)e.y; _Float16 l1 = (_Float16)(e.y - (float)h1);
            _Float16 h2 = (_Float16)e.z; _Float16 l2 = (_Float16)(e.z - (float)h2);
            _Float16 h3 = (_Float16)e.w; _Float16 l3 = (_Float16)(e.w - (float)h3);
            unsigned xr = (unsigned)((c & 7) << 4);
            unsigned base = (unsigned)(c * 128) + (((unsigned)(q * 8)) ^ xr);
            *(uint2*)(eb + OFF_EH + base) = make_uint2(pk2(h0, h1), pk2(h2, h3));
            *(uint2*)(eb + OFF_EL + base) = make_uint2(pk2(l0, l1), pk2(l2, l3));

            float p = e.x * e.x;
            p = fmaf(e.y, e.y, p);
            p = fmaf(e.z, e.z, p);
            p = fmaf(e.w, e.w, p);
            p += __shfl_xor(p, 1);
            p += __shfl_xor(p, 2);
            p += __shfl_xor(p, 4);
            p += __shfl_xor(p, 8);
            if (q == 0) e2L[c] = p;
        }
    }
    __syncthreads();

    // P3: ONE pass over the codebook for all 4 row-tiles.
    // Dekker fp16 split, 3 product terms (lo*lo ~1.5e-5 << MARGIN dropped).
    // C layout: col=lane&15 -> x-row; row=(lane>>4)*4+j -> code.
#define DECL(rt) \
    float s1_##rt = INFINITY, s2_##rt = INFINITY; \
    int   i1_##rt = 0, i2_##rt = 0;
    RT_ALL(DECL)
#undef DECL
#define UPD(rt, s, ki) { \
    bool lt1 = (s) < s1_##rt; bool lt2 = (s) < s2_##rt; \
    s2_##rt = lt1 ? s1_##rt : (lt2 ? (s) : s2_##rt); \
    i2_##rt = lt1 ? i1_##rt : (lt2 ? (ki) : i2_##rt); \
    s1_##rt = lt1 ? (s) : s1_##rt; \
    i1_##rt = lt1 ? (ki) : i1_##rt; }

    const char* ebase = s_arena;
    for (int cb = 0; cb < 8; ++cb) {
        const int cbBase = cb * 64 + fq * 4;

#define LDE2(ct) f32x4 e2q##ct = *(const f32x4*)(e2L + cb * 64 + ct * 16 + fq * 4);
        CT_ALL(LDE2)
#undef LDE2

#define LDE(ct) \
        const int c##ct = cb * 64 + ct * 16 + fr; \
        const char* rb##ct = ebase + c##ct * 128; \
        const unsigned xr##ct = (unsigned)((c##ct & 7) << 4); \
        f16x8 eh##ct##_0 = *(const f16x8*)(rb##ct + OFF_EH + (((unsigned)(fq*16 +  0)) ^ xr##ct)); \
        f16x8 eh##ct##_1 = *(const f16x8*)(rb##ct + OFF_EH + (((unsigned)(fq*16 + 64)) ^ xr##ct)); \
        f16x8 el##ct##_0 = *(const f16x8*)(rb##ct + OFF_EL + (((unsigned)(fq*16 +  0)) ^ xr##ct)); \
        f16x8 el##ct##_1 = *(const f16x8*)(rb##ct + OFF_EL + (((unsigned)(fq*16 + 64)) ^ xr##ct));
        CT_ALL(LDE)
#undef LDE

        // 4 row-tiles x 4 code-tiles x 6 MFMA, each e-frag reused 4x
#define ACC1(rt, ct) \
        f32x4 a##rt##_##ct = {0.f, 0.f, 0.f, 0.f}; \
        a##rt##_##ct = MFMA(eh##ct##_0, xh##rt##_0, a##rt##_##ct); \
        a##rt##_##ct = MFMA(eh##ct##_1, xh##rt##_1, a##rt##_##ct); \
        a##rt##_##ct = MFMA(el##ct##_0, xh##rt##_0, a##rt##_##ct); \
        a##rt##_##ct = MFMA(el##ct##_1, xh##rt##_1, a##rt##_##ct); \
        a##rt##_##ct = MFMA(eh##ct##_0, xl##rt##_0, a##rt##_##ct); \
        a##rt##_##ct = MFMA(eh##ct##_1, xl##rt##_1, a##rt##_##ct);
#define ACC_CT(ct) ACC1(0, ct) ACC1(1, ct) ACC1(2, ct) ACC1(3, ct)
        CT_ALL(ACC_CT)
#undef ACC_CT
#undef ACC1

#define SCJ(rt, ct, j) { \
        float s = fmaf(-2.f, a##rt##_##ct[j], e2q##ct[j]); \
        int ki = cbBase + ct * 16 + j; \
        UPD(rt, s, ki) }
#define SC4(rt, ct) SCJ(rt, ct, 0) SCJ(rt, ct, 1) SCJ(rt, ct, 2) SCJ(rt, ct, 3)
#define SC_CT(ct) SC4(0, ct) SC4(1, ct) SC4(2, ct) SC4(3, ct)
        CT_ALL(SC_CT)
#undef SC_CT
#undef SC4
#undef SCJ
    }

    // cross-lane top-2 merge (fq groups 0..3 see disjoint codes)
#define MERGE(rt, off) { \
    float b1 = __shfl_xor(s1_##rt, off); int bi1 = __shfl_xor(i1_##rt, off); \
    float b2 = __shfl_xor(s2_##rt, off); int bi2 = __shfl_xor(i2_##rt, off); \
    bool bf = (b1 < s1_##rt) || (b1 == s1_##rt && bi1 < i1_##rt); \
    float c1 = bf ? b1 : s1_##rt; int ci1 = bf ? bi1 : i1_##rt; \
    float lw = bf ? s1_##rt : b1; int lwi = bf ? i1_##rt : bi1; \
    float d2 = bf ? b2 : s2_##rt; int di2 = bf ? bi2 : i2_##rt; \
    bool ds = (d2 < lw) || (d2 == lw && di2 < lwi); \
    s1_##rt = c1; i1_##rt = ci1; \
    s2_##rt = ds ? d2 : lw; i2_##rt = ds ? di2 : lwi; }
#define MERGE2(rt) MERGE(rt, 16) MERGE(rt, 32)
    RT_ALL(MERGE2)
#undef MERGE2
#undef MERGE

    if (fq == 0) {
#define WRT(rt) \
        s_idxL[w * 64 + rt * 16 + fr] = i1_##rt; \
        s_refL[w * 64 + rt * 16 + fr] = (s2_##rt - s1_##rt < MARGIN) ? i2_##rt : -1;
        RT_ALL(WRT)
#undef WRT
    }
#undef UPD

    // P4: fp64 tie-refine (rare) + dual final-idx write
    {
        const int n = blockIdx.x * ROWS_PER_BLK + tid;
        const int b = n >> 12, hw = n & 4095;
        int i1 = s_idxL[tid];
        const int ir = s_refL[tid];
        if (ir >= 0) {   // near-tie: exact fp64 distance from global x
            const float* xin = in + (size_t)b * 262144 + hw;
            double dA = 0.0, dB = 0.0;
            const float* eA = emb + i1 * D;
            const float* eB = emb + ir * D;
            for (int d = 0; d < D; ++d) {
                double xv = (double)xin[d * 4096];
                double tA = xv - (double)eA[d]; dA = fma(tA, tA, dA);
                double tB = xv - (double)eB[d]; dB = fma(tB, tB, dB);
            }
            if (dB < dA || (dB == dA && ir < i1)) i1 = ir;
        }
        const float fbits = __int_as_float(i1);
        enc_out[(size_t)n * K] = fbits;                 // for enc-blocks
        quant_out[(size_t)b * 262144 + hw] = fbits;     // for quant-blocks
    }
}

// K23: ONE grid, two block types, interleaved 4 enc : 1 quant so the
// 268 MB one-hot stream and the 67 MB quant stream share the write pipe.
__global__ __launch_bounds__(256) void vq_out_kernel(
    const float* __restrict__ in,
    const float* __restrict__ emb,
    unsigned int* __restrict__ counts,
    unsigned long long* __restrict__ loss_acc,
    float* __restrict__ quant_out,
    float* __restrict__ enc)
{
    __shared__ unsigned int s_hist[K];
    __shared__ double s_red[256];
    const int tid = threadIdx.x;
    const int grp = blockIdx.x / 5;
    const int sub = blockIdx.x % 5;

    if (sub < 4) {
        // ---- enc block: 64 rows, one-hot NT expansion (dense 16B/lane) ----
        const int eb   = grp * 4 + sub;        // 0..2047
        const int wv   = tid >> 6;
        const int lane = tid & 63;
        const size_t row0 = (size_t)eb * 64 + (size_t)wv * 16;

        int idxs[16];
        #pragma unroll
        for (int i = 0; i < 16; ++i)
            idxs[i] = __float_as_int(enc[(row0 + i) * K]);

        const int c0 = lane * 4;
        #pragma unroll
        for (int i = 0; i < 16; ++i) {
            const int idx = idxs[i];
            float* rp = enc + (row0 + i) * K;
            f32x4 v0, v1;
            v0.x = (c0 + 0 == idx) ? 1.f : 0.f;
            v0.y = (c0 + 1 == idx) ? 1.f : 0.f;
            v0.z = (c0 + 2 == idx) ? 1.f : 0.f;
            v0.w = (c0 + 3 == idx) ? 1.f : 0.f;
            v1.x = (256 + c0 + 0 == idx) ? 1.f : 0.f;
            v1.y = (256 + c0 + 1 == idx) ? 1.f : 0.f;
            v1.z = (256 + c0 + 2 == idx) ? 1.f : 0.f;
            v1.w = (256 + c0 + 3 == idx) ? 1.f : 0.f;
            __builtin_nontemporal_store(v0, (f32x4*)(rp + c0));
            __builtin_nontemporal_store(v1, (f32x4*)(rp + 256 + c0));
        }
        return;
    }

    // ---- quant block: 256 rows -> hist + quant(NT) + loss ----
    const int n = grp * 256 + tid;             // grp = 0..511
    s_hist[tid] = 0u; s_hist[tid + 256] = 0u;
    __syncthreads();

    const int b = n >> 12, hw = n & 4095;
    const float* xin = in + (size_t)b * 262144 + hw;
    const int i1 = __float_as_int(quant_out[(size_t)b * 262144 + hw]);
    atomicAdd(&s_hist[i1], 1u);

    const float4* eq = (const float4*)(emb + (size_t)i1 * D);
    float* qout = quant_out + (size_t)b * 262144 + hw;
    float lsum = 0.f;
    #pragma unroll
    for (int i = 0; i < 16; ++i) {
        float4 q = eq[i];
        float x0 = xin[(4 * i + 0) * 4096], x1 = xin[(4 * i + 1) * 4096];
        float x2 = xin[(4 * i + 2) * 4096], x3 = xin[(4 * i + 3) * 4096];
        float d0 = q.x - x0; lsum = fmaf(d0, d0, lsum);
        float d1 = q.y - x1; lsum = fmaf(d1, d1, lsum);
        float d2 = q.z - x2; lsum = fmaf(d2, d2, lsum);
        float d3 = q.w - x3; lsum = fmaf(d3, d3, lsum);
        __builtin_nontemporal_store(q.x, &qout[(4 * i + 0) * 4096]);
        __builtin_nontemporal_store(q.y, &qout[(4 * i + 1) * 4096]);
        __builtin_nontemporal_store(q.z, &qout[(4 * i + 2) * 4096]);
        __builtin_nontemporal_store(q.w, &qout[(4 * i + 3) * 4096]);
    }

    s_red[tid] = (double)lsum;
    __syncthreads();
    for (int s = 128; s > 0; s >>= 1) {
        if (tid < s) s_red[tid] += s_red[tid + s];
        __syncthreads();
    }
    if (tid == 0) {
        unsigned long long q =
            (unsigned long long)(long long)llrint(s_red[0] * 1073741824.0);
        atomicAdd(loss_acc, q);
    }
    {
        unsigned int c0h = s_hist[tid];
        if (c0h) atomicAdd(&counts[tid], c0h);
        unsigned int c1h = s_hist[tid + 256];
        if (c1h) atomicAdd(&counts[tid + 256], c1h);
    }
}

__global__ __launch_bounds__(512) void vq_final_kernel(
    const unsigned int* __restrict__ counts,
    const unsigned long long* __restrict__ loss_acc,
    float* __restrict__ out_loss,
    float* __restrict__ out_perp)
{
    __shared__ double sp[512];
    int t = threadIdx.x;
    double p = (double)counts[t] / (double)N_ROWS;
    sp[t] = p * log(p + 1e-10);
    __syncthreads();
    for (int s = 256; s > 0; s >>= 1) {
        if (t < s) sp[t] += sp[t + s];
        __syncthreads();
    }
    if (t == 0) {
        double ls = (double)(long long)(*loss_acc) * (1.0 / 1073741824.0);
        *out_loss = (float)(0.25 * ls / 8388608.0);
        *out_perp = (float)exp(-sp[0]);
    }
}

extern "C" void kernel_launch(void* const* d_in, const int* in_sizes, int n_in,
                              void* d_out, int out_size, void* d_ws, size_t ws_size,
                              hipStream_t stream) {
    const float* in  = (const float*)d_in[0];
    const float* emb = (const float*)d_in[1];
    float* out = (float*)d_out;

    unsigned int* counts = (unsigned int*)d_ws;
    unsigned long long* loss_acc = (unsigned long long*)((char*)d_ws + 2048);

    hipMemsetAsync(d_ws, 0, 2056, stream);
    vq_dist_kernel<<<GRID, BLK, 0, stream>>>(in, emb, out + 1, out + 8388610);
    vq_out_kernel<<<2560, 256, 0, stream>>>(in, emb, counts, loss_acc,
                                            out + 1, out + 8388610);
    vq_final_kernel<<<1, 512, 0, stream>>>(counts, loss_acc, out, out + 8388609);
}

// Round 19
// 122.151 us; speedup vs baseline: 1.1089x; 1.0098x over previous
//
#include <hip/hip_runtime.h>
#include <math.h>

#define N_ROWS 131072   // 32*64*64
#define D 64
#define K 512
#define BLK 512                       // 8 waves (K1)
#define ROWS_PER_BLK 512
#define GRID (N_ROWS / ROWS_PER_BLK)  // 256 -> 1 block/CU for K1
#define MARGIN 4e-3f

// d_out layout (floats):
//   [0] loss ; [1..8388608] quantized NCHW ; [8388609] perplexity ;
//   [8388610..] encodings [131072,512]
// d_ws: [0,2048) counts u32[512]; [2048,2056) loss_acc u64 fixed-point

typedef __attribute__((ext_vector_type(8))) _Float16 f16x8;
typedef __attribute__((ext_vector_type(4))) float    f32x4;

#define MFMA(a, b, c) __builtin_amdgcn_mfma_f32_16x16x32_f16((a), (b), (c), 0, 0, 0)

// K1 LDS arena (139264 B): codebook region [0,131072) doubles as X staging.
#define OFF_EH   0        // [512 codes][128 B] fp16-hi, XOR-swizzled
#define OFF_EL   65536    // fp16-lo
#define OFF_XH   0        // phase A: [512 rows][128 B] fp16-hi (overwritten)
#define OFF_XL   65536    // phase A: fp16-lo
#define OFF_E2   131072   // f32[512]
#define OFF_HIST 133120   // u32[512]
#define OFF_RED  135168   // f64[512]
#define ARENA_SZ 139264

__device__ __forceinline__ unsigned pk2(_Float16 a, _Float16 b) {
    return (unsigned)__builtin_bit_cast(unsigned short, a) |
           ((unsigned)__builtin_bit_cast(unsigned short, b) << 16);
}

#define CT_ALL(M) M(0) M(1) M(2) M(3)
#define RT_ALL(M) M(0) M(1) M(2) M(3)

// K1: MFMA distance machine, single cb pass over 4 row-tiles (R18).
// R19: loss computed IN-K1 via the score identity ||x-e||^2 = s1 + ||x||^2
// (x2 accumulated during P0 staging; fp64-exact for refined rows), plus
// hist; each thread's own registers hold its row's (s1,i1,i2) after the
// merge, so the s_idx/s_ref LDS round-trip is gone. K23's quant blocks
// become pure writers (no x re-read anywhere downstream).
__global__ __launch_bounds__(BLK, 2) void vq_dist_kernel(
    const float* __restrict__ in,     // [32,64,64,64] NCHW
    const float* __restrict__ emb,    // [512,64]
    unsigned int* __restrict__ counts,
    unsigned long long* __restrict__ loss_acc,
    float* __restrict__ quant_out,    // NCHW
    float* __restrict__ enc_out)      // [N_ROWS, 512]
{
    __shared__ __align__(16) char s_arena[ARENA_SZ];
    float*        e2L    = (float*)(s_arena + OFF_E2);
    unsigned int* s_hstL = (unsigned int*)(s_arena + OFF_HIST);
    double*       s_redL = (double*)(s_arena + OFF_RED);

    const int tid  = threadIdx.x;
    const int lane = tid & 63;
    const int w    = tid >> 6;
    const int fr   = lane & 15;
    const int fq   = lane >> 4;

    // P0: stage x split into LDS [512 rows][128 B] fp16, XOR-swizzled.
    // Also accumulate this row's ||x||^2 in fp32 (for the loss identity).
    float x2 = 0.f;
    {
        const int nn = blockIdx.x * ROWS_PER_BLK + tid;
        const int bb = nn >> 12, hww = nn & 4095;
        const float* xp = in + (size_t)bb * 262144 + hww;
        char* xhW = s_arena + OFF_XH;
        char* xlW = s_arena + OFF_XL;
        const unsigned rbase = (unsigned)tid * 128u;
        const unsigned rxor  = (unsigned)((tid & 7) << 4);
        #pragma unroll
        for (int i = 0; i < 64; i += 2) {
            float f0 = xp[i * 4096];
            float f1 = xp[(i + 1) * 4096];
            x2 = fmaf(f0, f0, x2);
            x2 = fmaf(f1, f1, x2);
            _Float16 h0 = (_Float16)f0; _Float16 l0 = (_Float16)(f0 - (float)h0);
            _Float16 h1 = (_Float16)f1; _Float16 l1 = (_Float16)(f1 - (float)h1);
            unsigned off = rbase + (((unsigned)(i * 2)) ^ rxor);
            *(unsigned*)(xhW + off) = pk2(h0, h1);
            *(unsigned*)(xlW + off) = pk2(l0, l1);
        }
    }
    __syncthreads();

    // P1: load ALL 4 row-tiles' X fragments (matching XOR on 16B offsets)
    const char* xb = s_arena;
    const int xr0 = w * 64 + fr;
#define LDX1(t, half) \
    *(const f16x8*)(xb + OFF_XH + (unsigned)(xr0 + t * 16) * 128u + \
        (((unsigned)(fq * 16 + half * 64)) ^ ((unsigned)(((xr0 + t * 16) & 7) << 4))))
#define LDX1L(t, half) \
    *(const f16x8*)(xb + OFF_XL + (unsigned)(xr0 + t * 16) * 128u + \
        (((unsigned)(fq * 16 + half * 64)) ^ ((unsigned)(((xr0 + t * 16) & 7) << 4))))
#define LDXF(t) \
    f16x8 xh##t##_0 = LDX1(t, 0); \
    f16x8 xh##t##_1 = LDX1(t, 1); \
    f16x8 xl##t##_0 = LDX1L(t, 0); \
    f16x8 xl##t##_1 = LDX1L(t, 1);
    RT_ALL(LDXF)
#undef LDXF
#undef LDX1
#undef LDX1L
    __syncthreads();

    // P2: overwrite LDS with split codebook (XOR-swizzled rows); e2 in the
    // same sweep via 16-lane shfl_xor reduce; zero hist.
    {
        char* eb = s_arena;
        #pragma unroll
        for (int it = 0; it < 16; ++it) {
            int j = tid + it * 512;            // float4 index, 0..8191
            int c = j >> 4, q = j & 15;        // code, quad-within-row
            float4 e = ((const float4*)emb)[j];
            _Float16 h0 = (_Float16)e.x; _Float16 l0 = (_Float16)(e.x - (float)h0);
            _Float16 h1 = (_Float16)e.y; _Float16 l1 = (_Float16)(e.y - (float)h1);
            _Float16 h2 = (_Float16)e.z; _Float16 l2 = (_Float16)(e.z - (float)h2);
            _Float16 h3 = (_Float16)e.w; _Float16 l3 = (_Float16)(e.w - (float)h3);
            unsigned xr = (unsigned)((c & 7) << 4);
            unsigned base = (unsigned)(c * 128) + (((unsigned)(q * 8)) ^ xr);
            *(uint2*)(eb + OFF_EH + base) = make_uint2(pk2(h0, h1), pk2(h2, h3));
            *(uint2*)(eb + OFF_EL + base) = make_uint2(pk2(l0, l1), pk2(l2, l3));

            float p = e.x * e.x;
            p = fmaf(e.y, e.y, p);
            p = fmaf(e.z, e.z, p);
            p = fmaf(e.w, e.w, p);
            p += __shfl_xor(p, 1);
            p += __shfl_xor(p, 2);
            p += __shfl_xor(p, 4);
            p += __shfl_xor(p, 8);
            if (q == 0) e2L[c] = p;
        }
        s_hstL[tid] = 0u;
    }
    __syncthreads();

    // P3: ONE pass over the codebook for all 4 row-tiles.
    // Dekker fp16 split, 3 product terms (lo*lo ~1.5e-5 << MARGIN dropped).
    // C layout: col=lane&15 -> x-row; row=(lane>>4)*4+j -> code.
#define DECL(rt) \
    float s1_##rt = INFINITY, s2_##rt = INFINITY; \
    int   i1_##rt = 0, i2_##rt = 0;
    RT_ALL(DECL)
#undef DECL
#define UPD(rt, s, ki) { \
    bool lt1 = (s) < s1_##rt; bool lt2 = (s) < s2_##rt; \
    s2_##rt = lt1 ? s1_##rt : (lt2 ? (s) : s2_##rt); \
    i2_##rt = lt1 ? i1_##rt : (lt2 ? (ki) : i2_##rt); \
    s1_##rt = lt1 ? (s) : s1_##rt; \
    i1_##rt = lt1 ? (ki) : i1_##rt; }

    const char* ebase = s_arena;
    for (int cb = 0; cb < 8; ++cb) {
        const int cbBase = cb * 64 + fq * 4;

#define LDE2(ct) f32x4 e2q##ct = *(const f32x4*)(e2L + cb * 64 + ct * 16 + fq * 4);
        CT_ALL(LDE2)
#undef LDE2

#define LDE(ct) \
        const int c##ct = cb * 64 + ct * 16 + fr; \
        const char* rb##ct = ebase + c##ct * 128; \
        const unsigned xr##ct = (unsigned)((c##ct & 7) << 4); \
        f16x8 eh##ct##_0 = *(const f16x8*)(rb##ct + OFF_EH + (((unsigned)(fq*16 +  0)) ^ xr##ct)); \
        f16x8 eh##ct##_1 = *(const f16x8*)(rb##ct + OFF_EH + (((unsigned)(fq*16 + 64)) ^ xr##ct)); \
        f16x8 el##ct##_0 = *(const f16x8*)(rb##ct + OFF_EL + (((unsigned)(fq*16 +  0)) ^ xr##ct)); \
        f16x8 el##ct##_1 = *(const f16x8*)(rb##ct + OFF_EL + (((unsigned)(fq*16 + 64)) ^ xr##ct));
        CT_ALL(LDE)
#undef LDE

        // 4 row-tiles x 4 code-tiles x 6 MFMA, each e-frag reused 4x
#define ACC1(rt, ct) \
        f32x4 a##rt##_##ct = {0.f, 0.f, 0.f, 0.f}; \
        a##rt##_##ct = MFMA(eh##ct##_0, xh##rt##_0, a##rt##_##ct); \
        a##rt##_##ct = MFMA(eh##ct##_1, xh##rt##_1, a##rt##_##ct); \
        a##rt##_##ct = MFMA(el##ct##_0, xh##rt##_0, a##rt##_##ct); \
        a##rt##_##ct = MFMA(el##ct##_1, xh##rt##_1, a##rt##_##ct); \
        a##rt##_##ct = MFMA(eh##ct##_0, xl##rt##_0, a##rt##_##ct); \
        a##rt##_##ct = MFMA(eh##ct##_1, xl##rt##_1, a##rt##_##ct);
#define ACC_CT(ct) ACC1(0, ct) ACC1(1, ct) ACC1(2, ct) ACC1(3, ct)
        CT_ALL(ACC_CT)
#undef ACC_CT
#undef ACC1

#define SCJ(rt, ct, j) { \
        float s = fmaf(-2.f, a##rt##_##ct[j], e2q##ct[j]); \
        int ki = cbBase + ct * 16 + j; \
        UPD(rt, s, ki) }
#define SC4(rt, ct) SCJ(rt, ct, 0) SCJ(rt, ct, 1) SCJ(rt, ct, 2) SCJ(rt, ct, 3)
#define SC_CT(ct) SC4(0, ct) SC4(1, ct) SC4(2, ct) SC4(3, ct)
        CT_ALL(SC_CT)
#undef SC_CT
#undef SC4
#undef SCJ
    }

    // cross-lane top-2 merge (fq groups 0..3 see disjoint codes)
#define MERGE(rt, off) { \
    float b1 = __shfl_xor(s1_##rt, off); int bi1 = __shfl_xor(i1_##rt, off); \
    float b2 = __shfl_xor(s2_##rt, off); int bi2 = __shfl_xor(i2_##rt, off); \
    bool bf = (b1 < s1_##rt) || (b1 == s1_##rt && bi1 < i1_##rt); \
    float c1 = bf ? b1 : s1_##rt; int ci1 = bf ? bi1 : i1_##rt; \
    float lw = bf ? s1_##rt : b1; int lwi = bf ? i1_##rt : bi1; \
    float d2 = bf ? b2 : s2_##rt; int di2 = bf ? bi2 : i2_##rt; \
    bool ds = (d2 < lw) || (d2 == lw && di2 < lwi); \
    s1_##rt = c1; i1_##rt = ci1; \
    s2_##rt = ds ? d2 : lw; i2_##rt = ds ? di2 : lwi; }
#define MERGE2(rt) MERGE(rt, 16) MERGE(rt, 32)
    RT_ALL(MERGE2)
#undef MERGE2
#undef MERGE
#undef UPD

    // P4: thread tid's own row (w*64+lane) data lives in its rt=(lane>>4)
    // registers after the merge -- select, refine rare ties in fp64, then
    // loss via the identity ||x-e||^2 = s1 + x2, hist, dual idx write.
    {
        const int n = blockIdx.x * ROWS_PER_BLK + tid;
        const int b = n >> 12, hw = n & 4095;

#define REFV(rt) ((s2_##rt - s1_##rt < MARGIN) ? i2_##rt : -1)
        const int rt0 = lane >> 4;
        float s1own = (rt0 == 0) ? s1_0 : (rt0 == 1) ? s1_1 : (rt0 == 2) ? s1_2 : s1_3;
        int   i1own = (rt0 == 0) ? i1_0 : (rt0 == 1) ? i1_1 : (rt0 == 2) ? i1_2 : i1_3;
        int   irown = (rt0 == 0) ? REFV(0) : (rt0 == 1) ? REFV(1) : (rt0 == 2) ? REFV(2) : REFV(3);
#undef REFV

        double lrow;
        if (irown >= 0) {   // near-tie: exact fp64 distances from global x
            const float* xin = in + (size_t)b * 262144 + hw;
            double dA = 0.0, dB = 0.0;
            const float* eA = emb + i1own * D;
            const float* eB = emb + irown * D;
            for (int d = 0; d < D; ++d) {
                double xv = (double)xin[d * 4096];
                double tA = xv - (double)eA[d]; dA = fma(tA, tA, dA);
                double tB = xv - (double)eB[d]; dB = fma(tB, tB, dB);
            }
            if (dB < dA || (dB == dA && irown < i1own)) { i1own = irown; lrow = dB; }
            else lrow = dA;
        } else {
            lrow = (double)s1own + (double)x2;
        }

        atomicAdd(&s_hstL[i1own], 1u);
        s_redL[tid] = lrow;

        const float fbits = __int_as_float(i1own);
        enc_out[(size_t)n * K] = fbits;                 // for enc-blocks
        quant_out[(size_t)b * 262144 + hw] = fbits;     // for quant-blocks
    }

    // epilogue: loss tree-reduce (double) + hist flush
    __syncthreads();
    for (int s = BLK / 2; s > 0; s >>= 1) {
        if (tid < s) s_redL[tid] += s_redL[tid + s];
        __syncthreads();
    }
    if (tid == 0) {
        unsigned long long q =
            (unsigned long long)(long long)llrint(s_redL[0] * 1073741824.0);
        atomicAdd(loss_acc, q);
    }
    {
        unsigned int c = s_hstL[tid];
        if (c) atomicAdd(&counts[tid], c);
    }
}

// K23 (R19): both block types are now PURE WRITERS (no x reads, no LDS,
// no barriers). Interleaved 4 enc : 1 quant to share the write pipe.
__global__ __launch_bounds__(256) void vq_out_kernel(
    const float* __restrict__ emb,
    float* __restrict__ quant_out,
    float* __restrict__ enc)
{
    const int tid = threadIdx.x;
    const int grp = blockIdx.x / 5;
    const int sub = blockIdx.x % 5;

    if (sub < 4) {
        // ---- enc block: 64 rows, one-hot NT expansion (dense 16B/lane) ----
        const int eb   = grp * 4 + sub;        // 0..2047
        const int wv   = tid >> 6;
        const int lane = tid & 63;
        const size_t row0 = (size_t)eb * 64 + (size_t)wv * 16;

        int idxs[16];
        #pragma unroll
        for (int i = 0; i < 16; ++i)
            idxs[i] = __float_as_int(enc[(row0 + i) * K]);

        const int c0 = lane * 4;
        #pragma unroll
        for (int i = 0; i < 16; ++i) {
            const int idx = idxs[i];
            float* rp = enc + (row0 + i) * K;
            f32x4 v0, v1;
            v0.x = (c0 + 0 == idx) ? 1.f : 0.f;
            v0.y = (c0 + 1 == idx) ? 1.f : 0.f;
            v0.z = (c0 + 2 == idx) ? 1.f : 0.f;
            v0.w = (c0 + 3 == idx) ? 1.f : 0.f;
            v1.x = (256 + c0 + 0 == idx) ? 1.f : 0.f;
            v1.y = (256 + c0 + 1 == idx) ? 1.f : 0.f;
            v1.z = (256 + c0 + 2 == idx) ? 1.f : 0.f;
            v1.w = (256 + c0 + 3 == idx) ? 1.f : 0.f;
            __builtin_nontemporal_store(v0, (f32x4*)(rp + c0));
            __builtin_nontemporal_store(v1, (f32x4*)(rp + 256 + c0));
        }
        return;
    }

    // ---- quant block: 256 rows, pure NT write of the chosen emb row ----
    const int n = grp * 256 + tid;             // grp = 0..511
    const int b = n >> 12, hw = n & 4095;
    float* qout = quant_out + (size_t)b * 262144 + hw;
    const int i1 = __float_as_int(qout[0]);    // idx bits in the d0 slot
    const float4* eq = (const float4*)(emb + (size_t)i1 * D);
    #pragma unroll
    for (int i = 0; i < 16; ++i) {
        float4 q = eq[i];
        __builtin_nontemporal_store(q.x, &qout[(4 * i + 0) * 4096]);
        __builtin_nontemporal_store(q.y, &qout[(4 * i + 1) * 4096]);
        __builtin_nontemporal_store(q.z, &qout[(4 * i + 2) * 4096]);
        __builtin_nontemporal_store(q.w, &qout[(4 * i + 3) * 4096]);
    }
}

__global__ __launch_bounds__(512) void vq_final_kernel(
    const unsigned int* __restrict__ counts,
    const unsigned long long* __restrict__ loss_acc,
    float* __restrict__ out_loss,
    float* __restrict__ out_perp)
{
    __shared__ double sp[512];
    int t = threadIdx.x;
    double p = (double)counts[t] / (double)N_ROWS;
    sp[t] = p * log(p + 1e-10);
    __syncthreads();
    for (int s = 256; s > 0; s >>= 1) {
        if (t < s) sp[t] += sp[t + s];
        __syncthreads();
    }
    if (t == 0) {
        double ls = (double)(long long)(*loss_acc) * (1.0 / 1073741824.0);
        *out_loss = (float)(0.25 * ls / 8388608.0);
        *out_perp = (float)exp(-sp[0]);
    }
}

extern "C" void kernel_launch(void* const* d_in, const int* in_sizes, int n_in,
                              void* d_out, int out_size, void* d_ws, size_t ws_size,
                              hipStream_t stream) {
    const float* in  = (const float*)d_in[0];
    const float* emb = (const float*)d_in[1];
    float* out = (float*)d_out;

    unsigned int* counts = (unsigned int*)d_ws;
    unsigned long long* loss_acc = (unsigned long long*)((char*)d_ws + 2048);

    hipMemsetAsync(d_ws, 0, 2056, stream);
    vq_dist_kernel<<<GRID, BLK, 0, stream>>>(in, emb, counts, loss_acc,
                                             out + 1, out + 8388610);
    vq_out_kernel<<<2560, 256, 0, stream>>>(emb, out + 1, out + 8388610);
    vq_final_kernel<<<1, 512, 0, stream>>>(counts, loss_acc, out, out + 8388609);
}